// Round 3
// baseline (1876.803 us; speedup 1.0000x reference)
//
#include <hip/hip_runtime.h>

// ConvLSTM B=8,T=16,CIN=16,HID=64,H=W=64,K=3 'SAME' — single persistent kernel.
// 512 blocks (2/CU, residency guaranteed: VGPR<=256 via launch_bounds(256,2),
// LDS 41184B*2 < 160KB), hand-rolled device-scope grid barrier between steps.
// Per (b,y) block: Y[64px x 256n] MFMA GEMM, K = 9 taps x 96 padded ch.
// n = g*64+o, g in {f,i,g}, g==3 = o-gate linear (center tap only).
// c state lives in VGPRs across all 16 steps (exact MFMA C-layout).
// K-loop software-pipelined: next tap's A(LDS)/B(L2) prefetched during MFMAs.

#define B_ 8
#define T_ 16
#define CIN_ 16
#define HID_ 64
#define H_ 64
#define W_ 64
#define HW_ (H_*W_)
#define CTOT_ 80
#define XS_ROW 66
#define XS_CH 104                 // 96 used + 8 pad: 208B row stride -> ~2-way banks
#define XS_SIZE (3*XS_ROW*XS_CH)  // 20592 hw = 41184 B
#define CSTRIDE_ (B_*HID_*HW_)    // 2097152
#define NBLK 512

typedef __attribute__((ext_vector_type(8))) short short8;
typedef __attribute__((ext_vector_type(4))) float f32x4;

__device__ __forceinline__ unsigned short f2bf(float f){
    unsigned u = __float_as_uint(f);
    u = (u + 0x7FFFu + ((u >> 16) & 1u)) >> 16;   // RNE
    return (unsigned short)u;
}
__device__ __forceinline__ float sigm_(float v){ return 1.0f/(1.0f + __expf(-v)); }
__device__ __forceinline__ float tanh_(float v){ return 2.0f/(1.0f + __expf(-2.0f*v)) - 1.0f; }

struct Bar { unsigned cnt; unsigned gen; };

__device__ __forceinline__ void grid_barrier(Bar* bar){
    __syncthreads();
    if (threadIdx.x == 0){
        __threadfence();   // device-scope release: h writes visible cross-XCD
        unsigned g0 = __hip_atomic_load(&bar->gen, __ATOMIC_RELAXED, __HIP_MEMORY_SCOPE_AGENT);
        unsigned a  = __hip_atomic_fetch_add(&bar->cnt, 1u, __ATOMIC_ACQ_REL, __HIP_MEMORY_SCOPE_AGENT);
        if (a == NBLK - 1u){
            __hip_atomic_store(&bar->cnt, 0u, __ATOMIC_RELAXED, __HIP_MEMORY_SCOPE_AGENT);
            __hip_atomic_fetch_add(&bar->gen, 1u, __ATOMIC_RELEASE, __HIP_MEMORY_SCOPE_AGENT);
        } else {
            while (__hip_atomic_load(&bar->gen, __ATOMIC_ACQUIRE, __HIP_MEMORY_SCOPE_AGENT) == g0)
                __builtin_amdgcn_s_sleep(2);
        }
        __threadfence();   // acquire side: invalidate stale L1/L2 lines
    }
    __syncthreads();
}

__global__ __launch_bounds__(256, 2) void lstm_fused(
    const float* __restrict__ x,
    const float* __restrict__ Wf, const float* __restrict__ Wi,
    const float* __restrict__ Wc, const float* __restrict__ Wo,
    const float* __restrict__ bfp, const float* __restrict__ bip,
    const float* __restrict__ bcp, const float* __restrict__ bop,
    unsigned short* __restrict__ Wfrag,
    unsigned short* __restrict__ hbfA, unsigned short* __restrict__ hbfB,
    float* __restrict__ out, Bar* bar)
{
    __shared__ __align__(16) unsigned short Xs[XS_SIZE];
    const int tid = threadIdx.x;
    const int bx  = blockIdx.x;
    // XCD swizzle: consecutive blocks go to XCD bx%8 -> give XCD k the y-range [8k,8k+8)
    const int y = (bx & 7)*8 + ((bx >> 3) & 7);
    const int b = bx >> 6;
    const int lane = tid & 63;
    const int w    = tid >> 6;
    const int l15  = lane & 15;
    const int q    = lane >> 4;

    // ---- phase 0: build Wfrag in MFMA fragment order.
    // Wfrag: [tap 9][cc 3][ng 16] frags; frag = [lane][j] 512 hw.
    // n = ng*16 + (lane&15): g=n>>6, o=n&63; k-ch c = cc*32 + (lane>>4)*8 + j.
    for (int idx = bx*256 + tid; idx < 9*3*16*512; idx += NBLK*256){
        int j    = idx & 7;
        int ln   = (idx >> 3) & 63;
        int frag = idx >> 9;
        int ng = frag & 15;
        int tc = frag >> 4;
        int cc = tc % 3, tap = tc / 3;
        int n = ng*16 + (ln & 15);
        int g = n >> 6, o = n & 63;
        int c = cc*32 + ((ln >> 4) << 3) + j;
        int ky = tap / 3, kx = tap % 3;
        float v = 0.0f;
        if (c < CTOT_){
            if (g == 0)      v = Wf[((o*CTOT_ + c)*3 + ky)*3 + kx];
            else if (g == 1) v = Wi[((o*CTOT_ + c)*3 + ky)*3 + kx];
            else if (g == 2) v = Wc[((o*CTOT_ + c)*3 + ky)*3 + kx];
            else             v = (tap == 4) ? Wo[o*CTOT_ + c] : 0.0f;
        }
        Wfrag[idx] = f2bf(v);
    }

    const int o = w*16 + l15;
    const float bfv = bfp[o], biv = bip[o], bcv = bcp[o], bov = bop[o];
    float creg[4][4] = {{0,0,0,0},{0,0,0,0},{0,0,0,0},{0,0,0,0}};

    grid_barrier(bar);   // Wfrag visible everywhere

    // ---- pre-stage t=0: zero LDS, stage x(0)
    {
        uint4 z4; z4.x=z4.y=z4.z=z4.w=0u;
        for (int i = tid; i < XS_SIZE/8; i += 256) ((uint4*)Xs)[i] = z4;
        __syncthreads();
        const float* xt = x + ((size_t)b*T_ + 0)*CIN_*HW_;
        for (int tk = w; tk < 3*CIN_; tk += 4){
            int row = tk % 3, c = tk / 3;
            int yy = y + row - 1;
            if (yy >= 0 && yy < H_){
                float v = xt[c*HW_ + yy*W_ + lane];
                Xs[(row*XS_ROW + lane + 1)*XS_CH + c] = f2bf(v);
            }
        }
    }

    for (int t = 0; t < T_; ++t){
        // ---- stage h(t) (written at t-1, fenced by grid barrier)
        if (t > 0){
            const unsigned short* hin = (t & 1) ? hbfA : hbfB;
            for (int i = tid; i < 3*64*8; i += 256){
                int ch8 = i & 7, px = (i >> 3) & 63, row = i >> 9;
                int yy = y + row - 1;
                if (yy >= 0 && yy < H_){
                    uint4 v = *(const uint4*)(hin + (((size_t)b*H_ + yy)*W_ + px)*HID_ + ch8*8);
                    *(uint4*)(Xs + (row*XS_ROW + px + 1)*XS_CH + CIN_ + ch8*8) = v;
                }
            }
        }
        __syncthreads();

        // ---- K-loop, software-pipelined one tap ahead
        f32x4 acc[4][4];
        #pragma unroll
        for (int g = 0; g < 4; ++g)
            #pragma unroll
            for (int mf = 0; mf < 4; ++mf) acc[g][mf] = (f32x4)0.0f;

        const int ccmax = t ? 3 : 1;    // t==0: h==0, only x channel-chunk
        short8 aC[4], bC[4];
        {   // preload (cc=0, tap=0): ky=0, kx=0
            const unsigned short* ap = Xs + (size_t)l15*XS_CH + q*8;
            #pragma unroll
            for (int mf = 0; mf < 4; ++mf) aC[mf] = *(const short8*)(ap + (size_t)mf*16*XS_CH);
            const unsigned short* bp = Wfrag + (size_t)w*512 + lane*8;
            #pragma unroll
            for (int g = 0; g < 4; ++g)    bC[g] = *(const short8*)(bp + (size_t)g*4*512);
        }
        for (int cc = 0; cc < ccmax; ++cc){
            #pragma unroll 1
            for (int tap = 0; tap < 9; ++tap){
                int ncc = cc, ntap = tap + 1;
                if (ntap == 9){ ntap = 0; ++ncc; }
                const bool have_next = (ncc < ccmax);
                short8 aN[4], bN[4];
                if (have_next){
                    const int nky = ntap / 3, nkx = ntap - 3*(ntap/3);
                    const unsigned short* ap =
                        Xs + (size_t)(nky*XS_ROW + l15 + nkx)*XS_CH + ncc*32 + q*8;
                    #pragma unroll
                    for (int mf = 0; mf < 4; ++mf) aN[mf] = *(const short8*)(ap + (size_t)mf*16*XS_CH);
                    const unsigned short* bp =
                        Wfrag + ((size_t)((ntap*3 + ncc)*16 + w) << 9) + lane*8;
                    #pragma unroll
                    for (int g = 0; g < 4; ++g)    bN[g] = *(const short8*)(bp + ((size_t)g << 11));
                }
                #pragma unroll
                for (int g = 0; g < 4; ++g)
                    #pragma unroll
                    for (int mf = 0; mf < 4; ++mf)
                        acc[g][mf] = __builtin_amdgcn_mfma_f32_16x16x32_bf16(
                                         aC[mf], bC[g], acc[g][mf], 0, 0, 0);
                if (have_next){
                    #pragma unroll
                    for (int mf = 0; mf < 4; ++mf) aC[mf] = aN[mf];
                    #pragma unroll
                    for (int g = 0; g < 4; ++g)    bC[g] = bN[g];
                }
            }
        }

        // ---- epilogue: gates, c update in registers, emit h
        unsigned short* hout = (t & 1) ? hbfB : hbfA;
        #pragma unroll
        for (int mf = 0; mf < 4; ++mf){
            #pragma unroll
            for (int r = 0; r < 4; ++r){
                const int m = mf*16 + q*4 + r;
                const float fv = sigm_(acc[0][mf][r] + bfv);
                const float iv = sigm_(acc[1][mf][r] + biv);
                const float gv = tanh_(acc[2][mf][r] + bcv);
                const float ov = sigm_(acc[3][mf][r] + bov);
                const float cn = creg[mf][r]*fv + iv*gv;
                creg[mf][r] = cn;
                const float hn = tanh_(cn)*ov;
                if (t < T_-1){
                    hout[(((size_t)b*H_ + y)*W_ + m)*HID_ + o] = f2bf(hn);
                } else {
                    const size_t oidx = (((size_t)b*HID_ + o)*H_ + y)*W_ + m;
                    out[oidx] = hn;
                    out[CSTRIDE_ + oidx] = cn;
                }
            }
        }

        if (t < T_-1){
            __syncthreads();                      // all waves done reading Xs
            uint4 z4; z4.x=z4.y=z4.z=z4.w=0u;
            for (int i = tid; i < XS_SIZE/8; i += 256) ((uint4*)Xs)[i] = z4;
            __syncthreads();
            // stage x(t+1) now: its load latency overlaps the barrier spin
            const float* xt = x + ((size_t)b*T_ + (t+1))*CIN_*HW_;
            for (int tk = w; tk < 3*CIN_; tk += 4){
                int row = tk % 3, c = tk / 3;
                int yy = y + row - 1;
                if (yy >= 0 && yy < H_){
                    float v = xt[c*HW_ + yy*W_ + lane];
                    Xs[(row*XS_ROW + lane + 1)*XS_CH + c] = f2bf(v);
                }
            }
            grid_barrier(bar);                    // h(t) visible to neighbors
        }
    }
}

extern "C" void kernel_launch(void* const* d_in, const int* in_sizes, int n_in,
                              void* d_out, int out_size, void* d_ws, size_t ws_size,
                              hipStream_t stream){
    const float* x  = (const float*)d_in[0];
    const float* Wf = (const float*)d_in[1];
    const float* bf = (const float*)d_in[2];
    const float* Wi = (const float*)d_in[3];
    const float* bi = (const float*)d_in[4];
    const float* Wc = (const float*)d_in[5];
    const float* bc = (const float*)d_in[6];
    const float* Wo = (const float*)d_in[7];
    const float* bo = (const float*)d_in[8];

    // ws: Wfrag 442368 B | hbfA 4 MB | hbfB 4 MB | Bar
    unsigned short* Wfrag = (unsigned short*)d_ws;
    unsigned short* hbfA  = (unsigned short*)((char*)d_ws + 442368);
    unsigned short* hbfB  = hbfA + CSTRIDE_;
    Bar* bar = (Bar*)((char*)d_ws + 442368 + 2*4194304);

    hipMemsetAsync(bar, 0, sizeof(Bar), stream);   // ws is poisoned 0xAA each replay

    hipLaunchKernelGGL(lstm_fused, dim3(NBLK), dim3(256), 0, stream,
                       x, Wf, Wi, Wc, Wo, bf, bi, bc, bo,
                       Wfrag, hbfA, hbfB, (float*)d_out, bar);
}

// Round 5
// 428.680 us; speedup vs baseline: 4.3781x; 4.3781x over previous
//
#include <hip/hip_runtime.h>

// ConvLSTM B=8,T=16,CIN=16,HID=64,H=W=64,K=3 'SAME' — 16-launch bf16 MFMA.
// Round-3 lesson: persistent kernel + device barrier = ~90us/barrier regression;
// stream-ordered launches are the cheap grid barrier. This round: half-row
// blocks (M=32) -> 1024 blocks = 4 blocks/CU (16 waves/CU), bias folded as
// constant channel 80 at center tap, o-gate MFMAs only at center tap,
// x pre-converted to bf16 channel-last, c updated in place (channel-last fp32).

#define B_ 8
#define T_ 16
#define CIN_ 16
#define HID_ 64
#define H_ 64
#define W_ 64
#define HW_ (H_*W_)
#define CTOT_ 80
#define XS_ROW 34                 // 32 px + 2 halo
#define XS_CH 104                 // 96 K-channels + 8 pad
#define XS_SIZE (3*XS_ROW*XS_CH)  // 10608 hw = 21216 B
#define CSTRIDE_ (B_*HID_*HW_)    // 2097152

typedef __attribute__((ext_vector_type(8))) short short8;
typedef __attribute__((ext_vector_type(4))) float f32x4;

__device__ __forceinline__ unsigned short f2bf(float f){
    unsigned u = __float_as_uint(f);
    u = (u + 0x7FFFu + ((u >> 16) & 1u)) >> 16;   // RNE
    return (unsigned short)u;
}
__device__ __forceinline__ float sigm_(float v){ return 1.0f/(1.0f + __expf(-v)); }
__device__ __forceinline__ float tanh_(float v){ return 2.0f/(1.0f + __expf(-2.0f*v)) - 1.0f; }

// Wfrag: [tap 9][cc 3][ng 16] frags of 512 hw ([lane][j]).
// n = ng*16+(lane&15): g=n>>6, o=n&63; k-ch c = cc*32+(lane>>4)*8+j.
// Bias folded at c==80 (constant-1 A channel), center tap only.
__global__ void prep_wfrag(const float* __restrict__ Wf, const float* __restrict__ Wi,
                           const float* __restrict__ Wc, const float* __restrict__ Wo,
                           const float* __restrict__ bf, const float* __restrict__ bi,
                           const float* __restrict__ bc, const float* __restrict__ bo,
                           unsigned short* __restrict__ Wfrag){
    int idx = blockIdx.x*256 + threadIdx.x;          // 864*256 = 221184 exact
    int j    = idx & 7;
    int lane = (idx >> 3) & 63;
    int frag = idx >> 9;
    int ng = frag & 15;
    int tc = frag >> 4;
    int cc = tc % 3, tap = tc / 3;
    int n = ng*16 + (lane & 15);
    int g = n >> 6, o = n & 63;
    int c = cc*32 + ((lane >> 4) << 3) + j;
    int ky = tap / 3, kx = tap % 3;
    float v = 0.0f;
    if (c < CTOT_){
        if (g == 0)      v = Wf[((o*CTOT_ + c)*3 + ky)*3 + kx];
        else if (g == 1) v = Wi[((o*CTOT_ + c)*3 + ky)*3 + kx];
        else if (g == 2) v = Wc[((o*CTOT_ + c)*3 + ky)*3 + kx];
        else             v = (tap == 4) ? Wo[o*CTOT_ + c] : 0.0f;
    } else if (c == CTOT_ && tap == 4){              // bias channel
        v = (g==0) ? bf[o] : (g==1) ? bi[o] : (g==2) ? bc[o] : bo[o];
    }
    Wfrag[idx] = f2bf(v);
}

// x[b][t][c][y][px] fp32 -> xbf[b][t][y][px][c16] bf16 (vector-stageable)
__global__ void prep_xbf(const float* __restrict__ x, unsigned short* __restrict__ xbf){
    int idx = blockIdx.x*256 + threadIdx.x;          // 524288 = (b,t,y,px) flat
    int px = idx & 63;
    int y  = (idx >> 6) & 63;
    int bt = idx >> 12;
    const float* src = x + (size_t)bt*CIN_*HW_ + y*W_ + px;
    unsigned short tmp[16];
    #pragma unroll
    for (int c = 0; c < 16; ++c) tmp[c] = f2bf(src[(size_t)c*HW_]);
    uint4* dst = (uint4*)(xbf + (size_t)idx*16);
    dst[0] = *(uint4*)(tmp);
    dst[1] = *(uint4*)(tmp + 8);
}

__global__ __launch_bounds__(256, 4) void lstm_step(
    const unsigned short* __restrict__ xbf,
    const unsigned short* __restrict__ Wfrag,
    float* __restrict__ cbuf,                        // [b][y][px][o] fp32, in place
    const unsigned short* __restrict__ hin,          // [b][y][px][o] bf16
    unsigned short* __restrict__ hout,
    float* __restrict__ out,                         // [h|c] std layout, t==15 only
    int t)
{
    __shared__ __align__(16) unsigned short Xs[XS_SIZE];
    const int id   = blockIdx.x;
    // XCD swizzle: id&7 -> XCD; give each XCD a contiguous 8-row y band so
    // y+-1 halo reads stay XCD-local.
    const int xcd  = id & 7;
    const int jj   = id >> 3;
    const int y    = xcd*8 + (jj & 7);
    const int b    = (jj >> 3) & 7;
    const int half = jj >> 6;
    const int x0   = half*32;
    const int tid  = threadIdx.x;
    const int lane = tid & 63;
    const int w    = tid >> 6;
    const int l15  = lane & 15;
    const int q    = lane >> 4;

    // ---- zero LDS (SAME-pad borders + pad channels)
    uint4 z4; z4.x=z4.y=z4.z=z4.w=0u;
    for (int i = tid; i < XS_SIZE/8; i += 256) ((uint4*)Xs)[i] = z4;
    __syncthreads();

    // ---- stage x: 3 rows x 34 px x 2 ch-chunks = 204 uint4 copies
    for (int i = tid; i < 204; i += 256){
        int row = i/68, rem = i - row*68;
        int px = rem >> 1, ch8 = rem & 1;
        int yy = y + row - 1, pxg = x0 + px - 1;
        if (yy >= 0 && yy < H_ && pxg >= 0 && pxg < W_){
            uint4 v = *(const uint4*)(xbf + ((((size_t)(b*T_ + t)*H_ + yy)*W_ + pxg)*16 + ch8*8));
            *(uint4*)(Xs + (row*XS_ROW + px)*XS_CH + ch8*8) = v;
        }
    }
    // ---- stage h: 3 x 34 x 8 = 816 uint4 copies (skip t==0: stays zero)
    if (t > 0){
        for (int i = tid; i < 816; i += 256){
            int row = i/272, rem = i - row*272;
            int px = rem >> 3, ch8 = rem & 7;
            int yy = y + row - 1, pxg = x0 + px - 1;
            if (yy >= 0 && yy < H_ && pxg >= 0 && pxg < W_){
                uint4 v = *(const uint4*)(hin + ((((size_t)b*H_ + yy)*W_ + pxg)*HID_ + ch8*8));
                *(uint4*)(Xs + (row*XS_ROW + px)*XS_CH + CIN_ + ch8*8) = v;
            }
        }
    }
    // ---- constant-1 bias channel (ch 80); OOB positions only feed zero weights
    for (int i = tid; i < 3*XS_ROW; i += 256)
        Xs[i*XS_CH + CTOT_] = 0x3F80;                // bf16 1.0
    __syncthreads();

    // ---- K-loop: 27 (cc,tap) iters, one-ahead pipelined; g=3 center tap only
    f32x4 acc[4][2];
    #pragma unroll
    for (int g = 0; g < 4; ++g){ acc[g][0] = (f32x4)0.0f; acc[g][1] = (f32x4)0.0f; }

    short8 aC[2], bC[3], bO;
    {   // preload (cc=0, tap=0): ky=0, kx=0
        const unsigned short* ap = Xs + (size_t)l15*XS_CH + q*8;
        aC[0] = *(const short8*)(ap);
        aC[1] = *(const short8*)(ap + 16*XS_CH);
        const unsigned short* bp = Wfrag + (size_t)w*512 + lane*8;
        #pragma unroll
        for (int g = 0; g < 3; ++g) bC[g] = *(const short8*)(bp + ((size_t)g << 11));
    }
    for (int cc = 0; cc < 3; ++cc){
        #pragma unroll 1
        for (int tap = 0; tap < 9; ++tap){
            int ncc = cc, ntap = tap + 1;
            if (ntap == 9){ ntap = 0; ++ncc; }
            const bool have = (ncc < 3);
            short8 aN[2], bN[3];
            if (have){
                const int nky = ntap/3, nkx = ntap - 3*(ntap/3);
                const unsigned short* ap =
                    Xs + (size_t)(nky*XS_ROW + l15 + nkx)*XS_CH + ncc*32 + q*8;
                aN[0] = *(const short8*)(ap);
                aN[1] = *(const short8*)(ap + 16*XS_CH);
                const unsigned short* bp =
                    Wfrag + ((size_t)((ntap*3 + ncc)*16 + w) << 9) + lane*8;
                #pragma unroll
                for (int g = 0; g < 3; ++g) bN[g] = *(const short8*)(bp + ((size_t)g << 11));
            }
            if (tap == 3)   // prefetch o-gate frag for tap 4
                bO = *(const short8*)(Wfrag + ((size_t)((4*3 + cc)*16 + 12 + w) << 9) + lane*8);
            if (tap == 4){  // o-gate: center tap only (covers bias ch too)
                acc[3][0] = __builtin_amdgcn_mfma_f32_16x16x32_bf16(aC[0], bO, acc[3][0], 0,0,0);
                acc[3][1] = __builtin_amdgcn_mfma_f32_16x16x32_bf16(aC[1], bO, acc[3][1], 0,0,0);
            }
            #pragma unroll
            for (int g = 0; g < 3; ++g){
                acc[g][0] = __builtin_amdgcn_mfma_f32_16x16x32_bf16(aC[0], bC[g], acc[g][0], 0,0,0);
                acc[g][1] = __builtin_amdgcn_mfma_f32_16x16x32_bf16(aC[1], bC[g], acc[g][1], 0,0,0);
            }
            if (have){
                aC[0]=aN[0]; aC[1]=aN[1];
                bC[0]=bN[0]; bC[1]=bN[1]; bC[2]=bN[2];
            }
        }
    }

    // ---- epilogue: wave-local gates; c in place, channel-last
    const int o = w*16 + l15;
    #pragma unroll
    for (int mf = 0; mf < 2; ++mf){
        #pragma unroll
        for (int r = 0; r < 4; ++r){
            const int m = mf*16 + q*4 + r;
            const int pxg = x0 + m;
            const float fv = sigm_(acc[0][mf][r]);
            const float iv = sigm_(acc[1][mf][r]);
            const float gv = tanh_(acc[2][mf][r]);
            const float ov = sigm_(acc[3][mf][r]);
            const size_t cidx = (((size_t)(b*H_ + y)*W_ + pxg)*HID_ + o);
            const float cprev = t ? cbuf[cidx] : 0.0f;
            const float cn = cprev*fv + iv*gv;
            const float hn = tanh_(cn)*ov;
            if (t < T_-1){
                cbuf[cidx] = cn;
                hout[cidx] = f2bf(hn);
            } else {
                const size_t oidx = ((((size_t)(b*HID_ + o))*H_ + y)*W_ + pxg);
                out[oidx] = hn;
                out[CSTRIDE_ + oidx] = cn;
            }
        }
    }
}

extern "C" void kernel_launch(void* const* d_in, const int* in_sizes, int n_in,
                              void* d_out, int out_size, void* d_ws, size_t ws_size,
                              hipStream_t stream){
    const float* x  = (const float*)d_in[0];
    const float* Wf = (const float*)d_in[1];
    const float* bf = (const float*)d_in[2];
    const float* Wi = (const float*)d_in[3];
    const float* bi = (const float*)d_in[4];
    const float* Wc = (const float*)d_in[5];
    const float* bc = (const float*)d_in[6];
    const float* Wo = (const float*)d_in[7];
    const float* bo = (const float*)d_in[8];

    // ws: Wfrag 442368 | xbf 16777216 | cbuf 8388608 | hbfA 4194304 | hbfB 4194304
    unsigned short* Wfrag = (unsigned short*)d_ws;
    unsigned short* xbf   = (unsigned short*)((char*)d_ws + 442368);
    float*          cbuf  = (float*)((char*)d_ws + 442368 + 16777216);
    unsigned short* hbfA  = (unsigned short*)((char*)d_ws + 442368 + 16777216 + 8388608);
    unsigned short* hbfB  = hbfA + CSTRIDE_;

    prep_wfrag<<<dim3(864), dim3(256), 0, stream>>>(Wf, Wi, Wc, Wo, bf, bi, bc, bo, Wfrag);
    prep_xbf<<<dim3(2048), dim3(256), 0, stream>>>(x, xbf);

    for (int t = 0; t < T_; ++t){
        const unsigned short* hi = (t & 1) ? hbfA : hbfB;   // t==0 never reads
        unsigned short*       ho = (t & 1) ? hbfB : hbfA;
        lstm_step<<<dim3(1024), dim3(256), 0, stream>>>(
            xbf, Wfrag, cbuf, hi, ho, (float*)d_out, t);
    }
}